// Round 1
// baseline (1299.233 us; speedup 1.0000x reference)
//
#include <hip/hip_runtime.h>

typedef unsigned short u16;
typedef unsigned int   u32;
typedef __attribute__((ext_vector_type(4))) float f32x4;
typedef __attribute__((ext_vector_type(8))) short bf16x8;

#define BB 4096
#define SS 31
#define CC 512
#define HH 8
#define MM (BB*SS)        // 126976 rows = 992 * 128
#define NPAIR (BB*HH)     // 32768 (b,h) pairs
#define SSQ (SS*SS)       // 961

__device__ __forceinline__ u16 f2bf(float f){
  union { float f; u32 u; } v; v.f = f;
  u32 r = (v.u + 0x7fffu + ((v.u >> 16) & 1u)) >> 16;  // RNE
  return (u16)r;
}
__device__ __forceinline__ float bf2f(u16 u){
  union { u32 u; float f; } v; v.u = ((u32)u) << 16;
  return v.f;
}
__device__ __forceinline__ void gload_lds16(const u16* g, u16* l){
  __builtin_amdgcn_global_load_lds((const __attribute__((address_space(1))) void*)g,
                                   (__attribute__((address_space(3))) void*)l, 16, 0, 0);
}

// ---------------- BN1: per-channel stats over (B,S) ----------------
__global__ __launch_bounds__(512) void bn1_stats_k(const float* __restrict__ x, float* __restrict__ acc){
  int c = threadIdx.x;  // 512 channels
  float s = 0.f, q = 0.f;
  for (int r = blockIdx.x; r < MM; r += gridDim.x){
    float v = x[(long)r*CC + c];
    s += v; q += v*v;
  }
  atomicAdd(&acc[c], s);
  atomicAdd(&acc[CC + c], q);
}

__global__ __launch_bounds__(512) void bn1_final_k(const float* __restrict__ acc, const float* __restrict__ w,
                                                   const float* __restrict__ b, float* __restrict__ scsh){
  int c = threadIdx.x;
  const float invN = 1.f / (float)MM;
  float mu  = acc[c] * invN;
  float var = acc[CC+c] * invN - mu*mu;
  float rs  = rsqrtf(var + 1e-5f);
  float sc  = w[c] * rs;
  scsh[c]    = sc;
  scsh[CC+c] = b[c] - mu*sc;
}

__global__ __launch_bounds__(256) void bn1_apply_k(const float* __restrict__ x, const float* __restrict__ scsh,
                                                   u16* __restrict__ xn){
  const int tot = MM*CC/8;
  int stride = gridDim.x * blockDim.x;
  for (int i = blockIdx.x*blockDim.x + threadIdx.x; i < tot; i += stride){
    const f32x4* xp = (const f32x4*)x;
    f32x4 a = xp[2l*i], b2 = xp[2l*i+1];
    int c = (i*8) & (CC-1);
    u16 r[8];
    #pragma unroll
    for (int j = 0; j < 4; j++) r[j]   = f2bf(a[j] *scsh[c+j]   + scsh[CC+c+j]);
    #pragma unroll
    for (int j = 0; j < 4; j++) r[4+j] = f2bf(b2[j]*scsh[c+4+j] + scsh[CC+c+4+j]);
    *(bf16x8*)(xn + 8l*i) = *(bf16x8*)r;
  }
}

// ---------------- weight fp32 -> bf16 ----------------
__global__ __launch_bounds__(256) void wconv_k(const float* __restrict__ a, const float* __restrict__ b,
                                               const float* __restrict__ c, const float* __restrict__ d,
                                               u16* __restrict__ o){
  int i = blockIdx.x*256 + threadIdx.x;
  if (i >= 4*CC*CC) return;
  int w = i >> 18;  // CC*CC = 262144 = 2^18
  const float* src = w==0 ? a : (w==1 ? b : (w==2 ? c : d));
  o[i] = f2bf(src[i & (CC*CC-1)]);
}

// ---------------- 128x128-tile bf16 MFMA GEMM, C[m,n] = sum_k A[m,k]*W[n,k] ----------------
// FINAL=0: three weights/outputs (q,k,v bf16).  FINAL=1: +bias +residual, fp32 out.
template<int FINAL>
__global__ __launch_bounds__(256) void gemm_bt_k(
    const u16* __restrict__ A,
    const u16* __restrict__ W0, const u16* __restrict__ W1, const u16* __restrict__ W2,
    u16* __restrict__ O0, u16* __restrict__ O1, u16* __restrict__ O2,
    const float* __restrict__ bias, const float* __restrict__ resid, float* __restrict__ out)
{
  __shared__ u16 As[128*64];
  __shared__ u16 Bs[128*64];
  const int t  = threadIdx.x;
  const int mt = blockIdx.y * 128;
  int ntile;
  const u16* Wsel; u16* Osel = nullptr;
  if (FINAL) { Wsel = W0; ntile = blockIdx.x; }
  else {
    int wi = blockIdx.x >> 2; ntile = blockIdx.x & 3;
    Wsel = wi==0 ? W0 : (wi==1 ? W1 : W2);
    Osel = wi==0 ? O0 : (wi==1 ? O1 : O2);
  }
  const u16* Ab = A    + (long)mt*CC;
  const u16* Bb = Wsel + (long)ntile*128*CC;
  const int lane = t & 63, wv = t >> 6;
  const int wr = wv >> 1, wc = wv & 1;
  const int lr = lane & 15, hi = lane >> 4;
  const int srow = t >> 3, scg = t & 7;   // staging: row 0..31, 16B chunk 0..7

  f32x4 acc[4][4];
  #pragma unroll
  for (int m=0;m<4;m++)
    #pragma unroll
    for (int n=0;n<4;n++)
      acc[m][n] = (f32x4){0.f,0.f,0.f,0.f};

  for (int kk = 0; kk < CC; kk += 64){
    #pragma unroll
    for (int s2 = 0; s2 < 4; s2++){
      int r2 = srow + 32*s2;
      gload_lds16(Ab + (long)r2*CC + kk + scg*8, &As[r2*64 + scg*8]);
      gload_lds16(Bb + (long)r2*CC + kk + scg*8, &Bs[r2*64 + scg*8]);
    }
    __syncthreads();
    #pragma unroll
    for (int ks = 0; ks < 2; ks++){
      bf16x8 af[4], bfr[4];
      #pragma unroll
      for (int m=0;m<4;m++) af[m]  = *(const bf16x8*)&As[(wr*64 + m*16 + lr)*64 + ks*32 + hi*8];
      #pragma unroll
      for (int n=0;n<4;n++) bfr[n] = *(const bf16x8*)&Bs[(wc*64 + n*16 + lr)*64 + ks*32 + hi*8];
      #pragma unroll
      for (int m=0;m<4;m++)
        #pragma unroll
        for (int n=0;n<4;n++)
          acc[m][n] = __builtin_amdgcn_mfma_f32_16x16x32_bf16(af[m], bfr[n], acc[m][n], 0, 0, 0);
    }
    __syncthreads();
  }
  #pragma unroll
  for (int m=0;m<4;m++){
    int gr = mt + wr*64 + m*16 + hi*4;
    #pragma unroll
    for (int n=0;n<4;n++){
      int gc = ntile*128 + wc*64 + n*16 + lr;
      #pragma unroll
      for (int j=0;j<4;j++){
        long off = (long)(gr + j)*CC + gc;
        if (FINAL) out[off] = acc[m][n][j] + bias[gc] + resid[off];
        else       Osel[off] = f2bf(acc[m][n][j]);
      }
    }
  }
}

// ---------------- energy: one wave per (b,h); 32x32 padded, 8 MFMAs ----------------
__global__ __launch_bounds__(256) void energy_k(const u16* __restrict__ q, const u16* __restrict__ k,
                                                float* __restrict__ e){
  const int wv = threadIdx.x >> 6, lane = threadIdx.x & 63;
  const int lr = lane & 15, hi = lane >> 4;
  #pragma unroll 1
  for (int it = 0; it < 4; it++){
    int p = blockIdx.x*4 + wv + 8192*it;   // 0..32767
    int b = p >> 3, h = p & 7;
    long base = ((long)b*SS)*CC + h*64;
    bf16x8 aq[2][2], ak[2][2];
    #pragma unroll
    for (int m=0;m<2;m++){
      int s = m*16 + lr;
      #pragma unroll
      for (int ks=0;ks<2;ks++){
        bf16x8 z = {0,0,0,0,0,0,0,0};
        aq[m][ks] = z; ak[m][ks] = z;
        if (s < SS){
          aq[m][ks] = *(const bf16x8*)&q[base + (long)s*CC + ks*32 + hi*8];
          ak[m][ks] = *(const bf16x8*)&k[base + (long)s*CC + ks*32 + hi*8];
        }
      }
    }
    f32x4 acc[2][2];
    #pragma unroll
    for (int m=0;m<2;m++)
      #pragma unroll
      for (int n=0;n<2;n++)
        acc[m][n] = (f32x4){0.f,0.f,0.f,0.f};
    #pragma unroll
    for (int ks=0;ks<2;ks++)
      #pragma unroll
      for (int m=0;m<2;m++)
        #pragma unroll
        for (int n=0;n<2;n++)
          acc[m][n] = __builtin_amdgcn_mfma_f32_16x16x32_bf16(aq[m][ks], ak[n][ks], acc[m][n], 0, 0, 0);
    long eb = (long)p*SSQ;
    #pragma unroll
    for (int m=0;m<2;m++)
      #pragma unroll
      for (int n=0;n<2;n++)
        #pragma unroll
        for (int j=0;j<4;j++){
          int s = m*16 + hi*4 + j, s2 = n*16 + lr;
          if (s < SS && s2 < SS) e[eb + s*SS + s2] = acc[m][n][j];
        }
  }
}

// ---------------- BN2 stats over (b,h) per (s,s') ----------------
__global__ __launch_bounds__(256) void bn2_stats_k(const float* __restrict__ e, float* __restrict__ acc2){
  int p = blockIdx.x*256 + threadIdx.x;  // position
  if (p >= SSQ) return;
  float s = 0.f, q = 0.f;
  int r0 = blockIdx.y * 128;
  for (int r = r0; r < r0 + 128; r++){
    float v = e[(long)r*SSQ + p];
    s += v; q += v*v;
  }
  atomicAdd(&acc2[p], s);
  atomicAdd(&acc2[1024 + p], q);
}

__global__ __launch_bounds__(256) void bn2_final_k(const float* __restrict__ acc2, const float* __restrict__ pw,
                                                   const float* __restrict__ pb, float* __restrict__ ss2){
  int p = blockIdx.x*256 + threadIdx.x;
  if (p >= SSQ) return;
  const float invN = 1.f/32768.f;
  const float invs = 0.04419417382415922f; // 1/sqrt(512)
  float mu  = acc2[p]*invN;
  float var = acc2[1024+p]*invN - mu*mu;
  float rs  = rsqrtf(var + 1e-5f);
  float srp = rs * pw[p];
  ss2[p]      = srp * invs;                 // scale on e (pen_w and 1/sqrt(C) folded)
  ss2[1024+p] = (pb[p] - mu*srp) * invs;    // shift
}

// ---------------- normalize + softmax + PV, one wave per (b,h) ----------------
__global__ __launch_bounds__(256) void attn_pv_k(const float* __restrict__ e, const float* __restrict__ ss2,
                                                 const u16* __restrict__ v, u16* __restrict__ ctx){
  __shared__ float sc2[SSQ], sh2[SSQ];
  __shared__ float att[4][SSQ];
  for (int i = threadIdx.x; i < SSQ; i += 256){ sc2[i] = ss2[i]; sh2[i] = ss2[1024+i]; }
  __syncthreads();
  const int wv = threadIdx.x >> 6, lane = threadIdx.x & 63;
  #pragma unroll 1
  for (int it = 0; it < 4; it++){
    int p = blockIdx.x*4 + wv + 8192*it;
    int b = p >> 3, h = p & 7;
    long eb = (long)p*SSQ;
    for (int i = lane; i < SSQ; i += 64)
      att[wv][i] = e[eb + i]*sc2[i] + sh2[i];      // normalized logits (already / sqrt(C))
    __syncthreads();
    if (lane < SS){
      int ro = lane*SS;
      float mx = -1e30f;
      for (int j=0;j<SS;j++) mx = fmaxf(mx, att[wv][ro + j]);
      float sum = 0.f;
      for (int j=0;j<SS;j++) sum += __expf(att[wv][ro + j] - mx);
      float inv = 1.f / sum;
      for (int j=0;j<SS;j++) att[wv][ro + j] = __expf(att[wv][ro + j] - mx) * inv;
    }
    __syncthreads();
    // PV: lane = head-dim channel
    long vbase = ((long)b*SS)*CC + h*64 + lane;
    float vr[SS];
    #pragma unroll
    for (int j=0;j<SS;j++) vr[j] = bf2f(v[vbase + (long)j*CC]);
    #pragma unroll 1
    for (int s=0;s<SS;s++){
      float c = 0.f;
      #pragma unroll
      for (int j=0;j<SS;j++) c += att[wv][s*SS + j] * vr[j];
      ctx[vbase + (long)s*CC] = f2bf(c);
    }
    __syncthreads();
  }
}

extern "C" void kernel_launch(void* const* d_in, const int* in_sizes, int n_in,
                              void* d_out, int out_size, void* d_ws, size_t ws_size,
                              hipStream_t stream)
{
  const float* x      = (const float*)d_in[0];
  const float* norm_w = (const float*)d_in[1];
  const float* norm_b = (const float*)d_in[2];
  const float* Wq     = (const float*)d_in[3];
  const float* Wk     = (const float*)d_in[4];
  const float* Wv     = (const float*)d_in[5];
  const float* Wout   = (const float*)d_in[6];
  const float* b_out  = (const float*)d_in[7];
  const float* pen_w  = (const float*)d_in[8];
  const float* pen_b  = (const float*)d_in[9];
  float* out = (float*)d_out;

  char* ws = (char*)d_ws;
  // workspace layout (bytes)
  const size_t WQB   = 0;                    // 4 weights bf16, contiguous: 4*262144*2 = 2 MB
  const size_t STATS = 2097152;              // zeroed region, 16 KB: bn1 sums [1024] f32 @+0, bn2 sums [2048] f32 @+4096
  const size_t SCSH1 = STATS + 16384;        // bn1 scale/shift [1024] f32
  const size_t SS2O  = SCSH1 + 4096;         // bn2 scale2/shift2 [2048] f32
  const size_t BIG0  = 2129920;              // xn bf16 (130,023,424 B); later aliased by energy f32 (125,960,192 B)
  const size_t BIGSZ = 130023424;
  u16*   wq    = (u16*)(ws + WQB);
  float* stats = (float*)(ws + STATS);
  float* acc2  = (float*)(ws + STATS + 4096);
  float* scsh  = (float*)(ws + SCSH1);
  float* ss2   = (float*)(ws + SS2O);
  u16*   xn    = (u16*)(ws + BIG0);
  float* e     = (float*)(ws + BIG0);            // alias: xn dead after QKV GEMM
  u16*   qb    = (u16*)(ws + BIG0 + BIGSZ);
  u16*   kb    = (u16*)(ws + BIG0 + 2*BIGSZ);
  u16*   vb    = (u16*)(ws + BIG0 + 3*BIGSZ);
  u16*   ctx   = qb;                             // alias: q dead after energy

  (void)hipMemsetAsync(ws + STATS, 0, 16384, stream);
  wconv_k<<<4096, 256, 0, stream>>>(Wq, Wk, Wv, Wout, wq);
  bn1_stats_k<<<512, 512, 0, stream>>>(x, stats);
  bn1_final_k<<<1, 512, 0, stream>>>(stats, norm_w, norm_b, scsh);
  bn1_apply_k<<<2048, 256, 0, stream>>>(x, scsh, xn);
  gemm_bt_k<0><<<dim3(12, 992), 256, 0, stream>>>(xn, wq, wq + 262144, wq + 2*262144,
                                                  qb, kb, vb, nullptr, nullptr, nullptr);
  energy_k<<<2048, 256, 0, stream>>>(qb, kb, e);
  bn2_stats_k<<<dim3(4, 256), 256, 0, stream>>>(e, acc2);
  bn2_final_k<<<4, 256, 0, stream>>>(acc2, pen_w, pen_b, ss2);
  attn_pv_k<<<2048, 256, 0, stream>>>(e, ss2, vb, ctx);
  gemm_bt_k<1><<<dim3(4, 992), 256, 0, stream>>>(ctx, wq + 3*262144, nullptr, nullptr,
                                                 nullptr, nullptr, nullptr, b_out, x, out);
}

// Round 3
// 1234.843 us; speedup vs baseline: 1.0521x; 1.0521x over previous
//
#include <hip/hip_runtime.h>

typedef unsigned short u16;
typedef unsigned int   u32;
typedef __attribute__((ext_vector_type(4))) float f32x4;
typedef __attribute__((ext_vector_type(8))) short bf16x8;

#define BB 4096
#define SS 31
#define CC 512
#define HH 8
#define MM (BB*SS)        // 126976 rows = 496 * 256
#define SSQ (SS*SS)       // 961

__device__ __forceinline__ u16 f2bf(float f){
  union { float f; u32 u; } v; v.f = f;
  u32 r = (v.u + 0x7fffu + ((v.u >> 16) & 1u)) >> 16;  // RNE
  return (u16)r;
}
__device__ __forceinline__ float bf2f(u16 u){
  union { u32 u; float f; } v; v.u = ((u32)u) << 16;
  return v.f;
}
__device__ __forceinline__ void gload_lds16(const u16* g, u16* l){
  __builtin_amdgcn_global_load_lds((const __attribute__((address_space(1))) void*)g,
                                   (__attribute__((address_space(3))) void*)l, 16, 0, 0);
}

// ---------------- BN1: per-channel stats over (B,S) ----------------
__global__ __launch_bounds__(512) void bn1_stats_k(const float* __restrict__ x, float* __restrict__ acc){
  int c = threadIdx.x;  // 512 channels
  float s = 0.f, q = 0.f;
  for (int r = blockIdx.x; r < MM; r += gridDim.x){
    float v = x[(long)r*CC + c];
    s += v; q += v*v;
  }
  atomicAdd(&acc[c], s);
  atomicAdd(&acc[CC + c], q);
}

__global__ __launch_bounds__(512) void bn1_final_k(const float* __restrict__ acc, const float* __restrict__ w,
                                                   const float* __restrict__ b, float* __restrict__ scsh){
  int c = threadIdx.x;
  const float invN = 1.f / (float)MM;
  float mu  = acc[c] * invN;
  float var = acc[CC+c] * invN - mu*mu;
  float rs  = rsqrtf(var + 1e-5f);
  float sc  = w[c] * rs;
  scsh[c]    = sc;
  scsh[CC+c] = b[c] - mu*sc;
}

__global__ __launch_bounds__(256) void bn1_apply_k(const float* __restrict__ x, const float* __restrict__ scsh,
                                                   u16* __restrict__ xn){
  const int tot = MM*CC/8;
  int stride = gridDim.x * blockDim.x;
  for (int i = blockIdx.x*blockDim.x + threadIdx.x; i < tot; i += stride){
    const f32x4* xp = (const f32x4*)x;
    f32x4 a = xp[2l*i], b2 = xp[2l*i+1];
    int c = (i*8) & (CC-1);
    u16 r[8];
    #pragma unroll
    for (int j = 0; j < 4; j++) r[j]   = f2bf(a[j] *scsh[c+j]   + scsh[CC+c+j]);
    #pragma unroll
    for (int j = 0; j < 4; j++) r[4+j] = f2bf(b2[j]*scsh[c+4+j] + scsh[CC+c+4+j]);
    *(bf16x8*)(xn + 8l*i) = *(bf16x8*)r;
  }
}

// ---------------- weight fp32 -> bf16 ----------------
__global__ __launch_bounds__(256) void wconv_k(const float* __restrict__ a, const float* __restrict__ b,
                                               const float* __restrict__ c, const float* __restrict__ d,
                                               u16* __restrict__ o){
  int i = blockIdx.x*256 + threadIdx.x;
  if (i >= 4*CC*CC) return;
  int w = i >> 18;  // CC*CC = 262144 = 2^18
  const float* src = w==0 ? a : (w==1 ? b : (w==2 ? c : d));
  o[i] = f2bf(src[i & (CC*CC-1)]);
}

// ---------------- 256x256-tile bf16 MFMA GEMM, deep-pipelined ----------------
// C[m,n] = sum_k A[m,k]*W[n,k].  BK=32, 16 K-tiles, 3 LDS buffers, stage 2 ahead.
// Per K-tile: issue 4 gload_lds slices (kt+2) -> 12 swizzled ds_read_b128 ->
// lgkmcnt(0) -> 32 MFMA (setprio) -> counted vmcnt(4) -> s_barrier.
// LDS swizzle (both-sides involution, rule 21): chunk ^= (row>>1)&3, applied as
// pre-swizzled GLOBAL source + swizzled read addr; gload_lds dest stays linear.
template<int FINAL>
__global__ __launch_bounds__(512,2) void gemm256_k(
    const u16* __restrict__ A,
    const u16* __restrict__ W0, const u16* __restrict__ W1, const u16* __restrict__ W2,
    u16* __restrict__ O0, u16* __restrict__ O1, u16* __restrict__ O2,
    const float* __restrict__ bias, const float* __restrict__ resid, float* __restrict__ out)
{
  __shared__ u16 lds[3*16384];   // 3 bufs x (A 256x32 + B 256x32) u16 = 96 KB
  const int t  = threadIdx.x;
  const int mt = blockIdx.y * 256;
  int nt; const u16* Wsel; u16* Osel = nullptr;
  if (FINAL) { Wsel = W0; nt = blockIdx.x; }
  else {
    int wi = blockIdx.x >> 1; nt = blockIdx.x & 1;
    Wsel = wi==0 ? W0 : (wi==1 ? W1 : W2);
    Osel = wi==0 ? O0 : (wi==1 ? O1 : O2);
  }
  const u16* Ab = A    + (long)mt*CC;
  const u16* Bb = Wsel + (long)nt*256*CC;
  const int lane = t & 63;
  const int wv = t >> 6, wm = wv >> 2, wn = wv & 3;   // 2x4 wave grid, wave tile 128x64
  const int lr = lane & 15, hi = lane >> 4;
  const int srow = t >> 2;                 // staging row 0..127
  const int sc   = t & 3;                  // dest 16B chunk within 64B row
  const int sg   = sc ^ ((t >> 3) & 3);    // pre-swizzled source chunk

  f32x4 acc[8][4];
  #pragma unroll
  for (int m=0;m<8;m++)
    #pragma unroll
    for (int n=0;n<4;n++)
      acc[m][n] = (f32x4){0.f,0.f,0.f,0.f};

  auto STAGE = [&](int kt){
    u16* Al = &lds[(kt % 3) * 16384];
    u16* Bl = Al + 8192;
    const u16* As = Ab + (long)srow*CC + kt*32 + sg*8;
    const u16* Bs = Bb + (long)srow*CC + kt*32 + sg*8;
    gload_lds16(As,          &Al[srow*32 + sc*8]);           // A rows 0..127
    gload_lds16(As + 128*CC, &Al[(srow+128)*32 + sc*8]);     // A rows 128..255
    gload_lds16(Bs,          &Bl[srow*32 + sc*8]);           // B rows 0..127
    gload_lds16(Bs + 128*CC, &Bl[(srow+128)*32 + sc*8]);     // B rows 128..255
  };

  STAGE(0); STAGE(1);
  asm volatile("s_waitcnt vmcnt(4)" ::: "memory");   // tile 0 landed (self); barrier collectivizes
  asm volatile("s_barrier" ::: "memory");

  const int chR = hi ^ ((lr >> 1) & 3);   // read-side swizzled chunk (frag-index independent)
  #pragma unroll 1
  for (int kt = 0; kt < 16; ++kt){
    if (kt < 14) STAGE(kt + 2);           // buf[(kt+2)%3]: last read as tile kt-1, already barrier'd
    const u16* Al = &lds[(kt % 3) * 16384];
    const u16* Bl = Al + 8192;
    bf16x8 af[8], bfr[4];
    #pragma unroll
    for (int m=0;m<8;m++){
      int row = wm*128 + m*16 + lr;
      af[m] = *(const bf16x8*)&Al[row*32 + chR*8];
    }
    #pragma unroll
    for (int n=0;n<4;n++){
      int row = wn*64 + n*16 + lr;
      bfr[n] = *(const bf16x8*)&Bl[row*32 + chR*8];
    }
    asm volatile("s_waitcnt lgkmcnt(0)" ::: "memory");
    __builtin_amdgcn_sched_barrier(0);    // rule 18: keep MFMA below the lgkmcnt
    __builtin_amdgcn_s_setprio(1);
    #pragma unroll
    for (int m=0;m<8;m++)
      #pragma unroll
      for (int n=0;n<4;n++)
        acc[m][n] = __builtin_amdgcn_mfma_f32_16x16x32_bf16(af[m], bfr[n], acc[m][n], 0, 0, 0);
    __builtin_amdgcn_s_setprio(0);
    if (kt < 14)       asm volatile("s_waitcnt vmcnt(4)" ::: "memory");  // tile kt+1 landed
    else if (kt == 14) asm volatile("s_waitcnt vmcnt(0)" ::: "memory");  // drain: tile 15 landed
    if (kt < 15)       asm volatile("s_barrier" ::: "memory");
  }

  #pragma unroll
  for (int m=0;m<8;m++){
    int gr = mt + wm*128 + m*16 + hi*4;
    #pragma unroll
    for (int n=0;n<4;n++){
      int gc = nt*256 + wn*64 + n*16 + lr;
      #pragma unroll
      for (int j=0;j<4;j++){
        long off = (long)(gr + j)*CC + gc;
        if (FINAL) out[off] = acc[m][n][j] + bias[gc] + resid[off];
        else       Osel[off] = f2bf(acc[m][n][j]);
      }
    }
  }
}

// ---------------- energy: one wave per (b,h); 32x32 padded, 8 MFMAs ----------------
__global__ __launch_bounds__(256) void energy_k(const u16* __restrict__ q, const u16* __restrict__ k,
                                                float* __restrict__ e){
  const int wv = threadIdx.x >> 6, lane = threadIdx.x & 63;
  const int lr = lane & 15, hi = lane >> 4;
  #pragma unroll 1
  for (int it = 0; it < 4; it++){
    int p = blockIdx.x*4 + wv + 8192*it;   // 0..32767
    int b = p >> 3, h = p & 7;
    long base = ((long)b*SS)*CC + h*64;
    bf16x8 aq[2][2], ak[2][2];
    #pragma unroll
    for (int m=0;m<2;m++){
      int s = m*16 + lr;
      #pragma unroll
      for (int ks=0;ks<2;ks++){
        bf16x8 z = {0,0,0,0,0,0,0,0};
        aq[m][ks] = z; ak[m][ks] = z;
        if (s < SS){
          aq[m][ks] = *(const bf16x8*)&q[base + (long)s*CC + ks*32 + hi*8];
          ak[m][ks] = *(const bf16x8*)&k[base + (long)s*CC + ks*32 + hi*8];
        }
      }
    }
    f32x4 acc[2][2];
    #pragma unroll
    for (int m=0;m<2;m++)
      #pragma unroll
      for (int n=0;n<2;n++)
        acc[m][n] = (f32x4){0.f,0.f,0.f,0.f};
    #pragma unroll
    for (int ks=0;ks<2;ks++)
      #pragma unroll
      for (int m=0;m<2;m++)
        #pragma unroll
        for (int n=0;n<2;n++)
          acc[m][n] = __builtin_amdgcn_mfma_f32_16x16x32_bf16(aq[m][ks], ak[n][ks], acc[m][n], 0, 0, 0);
    long eb = (long)p*SSQ;
    #pragma unroll
    for (int m=0;m<2;m++)
      #pragma unroll
      for (int n=0;n<2;n++)
        #pragma unroll
        for (int j=0;j<4;j++){
          int s = m*16 + hi*4 + j, s2 = n*16 + lr;
          if (s < SS && s2 < SS) e[eb + s*SS + s2] = acc[m][n][j];
        }
  }
}

// ---------------- BN2 stats over (b,h) per (s,s') ----------------
__global__ __launch_bounds__(256) void bn2_stats_k(const float* __restrict__ e, float* __restrict__ acc2){
  int p = blockIdx.x*256 + threadIdx.x;  // position
  if (p >= SSQ) return;
  float s = 0.f, q = 0.f;
  int r0 = blockIdx.y * 128;
  for (int r = r0; r < r0 + 128; r++){
    float v = e[(long)r*SSQ + p];
    s += v; q += v*v;
  }
  atomicAdd(&acc2[p], s);
  atomicAdd(&acc2[1024 + p], q);
}

__global__ __launch_bounds__(256) void bn2_final_k(const float* __restrict__ acc2, const float* __restrict__ pw,
                                                   const float* __restrict__ pb, float* __restrict__ ss2){
  int p = blockIdx.x*256 + threadIdx.x;
  if (p >= SSQ) return;
  const float invN = 1.f/32768.f;
  const float invs = 0.04419417382415922f; // 1/sqrt(512)
  float mu  = acc2[p]*invN;
  float var = acc2[1024+p]*invN - mu*mu;
  float rs  = rsqrtf(var + 1e-5f);
  float srp = rs * pw[p];
  ss2[p]      = srp * invs;                 // scale on e (pen_w and 1/sqrt(C) folded)
  ss2[1024+p] = (pb[p] - mu*srp) * invs;    // shift
}

// ---------------- normalize + softmax + PV, one wave per (b,h) ----------------
__global__ __launch_bounds__(256) void attn_pv_k(const float* __restrict__ e, const float* __restrict__ ss2,
                                                 const u16* __restrict__ v, u16* __restrict__ ctx){
  __shared__ float sc2[SSQ], sh2[SSQ];
  __shared__ float att[4][SSQ];
  for (int i = threadIdx.x; i < SSQ; i += 256){ sc2[i] = ss2[i]; sh2[i] = ss2[1024+i]; }
  __syncthreads();
  const int wv = threadIdx.x >> 6, lane = threadIdx.x & 63;
  #pragma unroll 1
  for (int it = 0; it < 4; it++){
    int p = blockIdx.x*4 + wv + 8192*it;
    int b = p >> 3, h = p & 7;
    long eb = (long)p*SSQ;
    for (int i = lane; i < SSQ; i += 64)
      att[wv][i] = e[eb + i]*sc2[i] + sh2[i];      // normalized logits (already / sqrt(C))
    __syncthreads();
    if (lane < SS){
      int ro = lane*SS;
      float mx = -1e30f;
      for (int j=0;j<SS;j++) mx = fmaxf(mx, att[wv][ro + j]);
      float sum = 0.f;
      for (int j=0;j<SS;j++) sum += __expf(att[wv][ro + j] - mx);
      float inv = 1.f / sum;
      for (int j=0;j<SS;j++) att[wv][ro + j] = __expf(att[wv][ro + j] - mx) * inv;
    }
    __syncthreads();
    // PV: lane = head-dim channel
    long vbase = ((long)b*SS)*CC + h*64 + lane;
    float vr[SS];
    #pragma unroll
    for (int j=0;j<SS;j++) vr[j] = bf2f(v[vbase + (long)j*CC]);
    #pragma unroll 1
    for (int s=0;s<SS;s++){
      float c = 0.f;
      #pragma unroll
      for (int j=0;j<SS;j++) c += att[wv][s*SS + j] * vr[j];
      ctx[vbase + (long)s*CC] = f2bf(c);
    }
    __syncthreads();
  }
}

extern "C" void kernel_launch(void* const* d_in, const int* in_sizes, int n_in,
                              void* d_out, int out_size, void* d_ws, size_t ws_size,
                              hipStream_t stream)
{
  const float* x      = (const float*)d_in[0];
  const float* norm_w = (const float*)d_in[1];
  const float* norm_b = (const float*)d_in[2];
  const float* Wq     = (const float*)d_in[3];
  const float* Wk     = (const float*)d_in[4];
  const float* Wv     = (const float*)d_in[5];
  const float* Wout   = (const float*)d_in[6];
  const float* b_out  = (const float*)d_in[7];
  const float* pen_w  = (const float*)d_in[8];
  const float* pen_b  = (const float*)d_in[9];
  float* out = (float*)d_out;

  char* ws = (char*)d_ws;
  // workspace layout (bytes)
  const size_t WQB   = 0;                    // 4 weights bf16, contiguous: 4*262144*2 = 2 MB
  const size_t STATS = 2097152;              // zeroed region, 16 KB: bn1 sums [1024] f32 @+0, bn2 sums [2048] f32 @+4096
  const size_t SCSH1 = STATS + 16384;        // bn1 scale/shift [1024] f32
  const size_t SS2O  = SCSH1 + 4096;         // bn2 scale2/shift2 [2048] f32
  const size_t BIG0  = 2129920;              // xn bf16 (130,023,424 B); later aliased by energy f32 (125,960,192 B)
  const size_t BIGSZ = 130023424;
  u16*   wq    = (u16*)(ws + WQB);
  float* stats = (float*)(ws + STATS);
  float* acc2  = (float*)(ws + STATS + 4096);
  float* scsh  = (float*)(ws + SCSH1);
  float* ss2   = (float*)(ws + SS2O);
  u16*   xn    = (u16*)(ws + BIG0);
  float* e     = (float*)(ws + BIG0);            // alias: xn dead after QKV GEMM
  u16*   qb    = (u16*)(ws + BIG0 + BIGSZ);
  u16*   kb    = (u16*)(ws + BIG0 + 2*BIGSZ);
  u16*   vb    = (u16*)(ws + BIG0 + 3*BIGSZ);
  u16*   ctx   = qb;                             // alias: q dead after energy

  (void)hipMemsetAsync(ws + STATS, 0, 16384, stream);
  wconv_k<<<4096, 256, 0, stream>>>(Wq, Wk, Wv, Wout, wq);
  bn1_stats_k<<<512, 512, 0, stream>>>(x, stats);
  bn1_final_k<<<1, 512, 0, stream>>>(stats, norm_w, norm_b, scsh);
  bn1_apply_k<<<2048, 256, 0, stream>>>(x, scsh, xn);
  gemm256_k<0><<<dim3(6, 496), 512, 0, stream>>>(xn, wq, wq + 262144, wq + 2*262144,
                                                 qb, kb, vb, nullptr, nullptr, nullptr);
  energy_k<<<2048, 256, 0, stream>>>(qb, kb, e);
  bn2_stats_k<<<dim3(4, 256), 256, 0, stream>>>(e, acc2);
  bn2_final_k<<<4, 256, 0, stream>>>(acc2, pen_w, pen_b, ss2);
  attn_pv_k<<<2048, 256, 0, stream>>>(e, ss2, vb, ctx);
  gemm256_k<1><<<dim3(2, 496), 512, 0, stream>>>(ctx, wq + 3*262144, nullptr, nullptr,
                                                 nullptr, nullptr, nullptr, b_out, x, out);
}

// Round 9
// 1214.336 us; speedup vs baseline: 1.0699x; 1.0169x over previous
//
#include <hip/hip_runtime.h>

typedef unsigned short u16;
typedef unsigned int   u32;
typedef __attribute__((ext_vector_type(4))) float f32x4;
typedef __attribute__((ext_vector_type(8))) short bf16x8;

#define BB 4096
#define SS 31
#define CC 512
#define HH 8
#define MM (BB*SS)        // 126976 rows = 496 * 256
#define SSQ (SS*SS)       // 961

__device__ __forceinline__ u16 f2bf(float f){
  union { float f; u32 u; } v; v.f = f;
  u32 r = (v.u + 0x7fffu + ((v.u >> 16) & 1u)) >> 16;  // RNE
  return (u16)r;
}
__device__ __forceinline__ float bf2f(u16 u){
  union { u32 u; float f; } v; v.u = ((u32)u) << 16;
  return v.f;
}
__device__ __forceinline__ void gload_lds16(const u16* g, u16* l){
  __builtin_amdgcn_global_load_lds((const __attribute__((address_space(1))) void*)g,
                                   (__attribute__((address_space(3))) void*)l, 16, 0, 0);
}

// ---------------- BN1: per-channel stats over (B,S), vectorized ----------------
__global__ __launch_bounds__(256) void bn1_stats_k(const float* __restrict__ x, float* __restrict__ acc){
  const int t = threadIdx.x;
  const int c = (t & 127) * 4;            // 4 channels per thread
  const int rof = t >> 7;                 // 2 rows per block-iter
  f32x4 s = (f32x4){0.f,0.f,0.f,0.f}, q = (f32x4){0.f,0.f,0.f,0.f};
  for (int r = blockIdx.x*2 + rof; r < MM; r += gridDim.x*2){
    f32x4 v = *(const f32x4*)(x + (long)r*CC + c);
    s += v; q += v*v;
  }
  __shared__ f32x4 red[256][2];
  red[t][0] = s; red[t][1] = q;
  __syncthreads();
  if (t < 128){
    s = red[t][0] + red[t+128][0];
    q = red[t][1] + red[t+128][1];
    int c0 = t*4;
    #pragma unroll
    for (int j=0;j<4;j++){
      atomicAdd(&acc[c0+j], s[j]);
      atomicAdd(&acc[CC+c0+j], q[j]);
    }
  }
}

__global__ __launch_bounds__(512) void bn1_final_k(const float* __restrict__ acc, const float* __restrict__ w,
                                                   const float* __restrict__ b, float* __restrict__ scsh){
  int c = threadIdx.x;
  const float invN = 1.f / (float)MM;
  float mu  = acc[c] * invN;
  float var = acc[CC+c] * invN - mu*mu;
  float rs  = rsqrtf(var + 1e-5f);
  float sc  = w[c] * rs;
  scsh[c]    = sc;
  scsh[CC+c] = b[c] - mu*sc;
}

__global__ __launch_bounds__(256) void bn1_apply_k(const float* __restrict__ x, const float* __restrict__ scsh,
                                                   u16* __restrict__ xn){
  const int tot = MM*CC/8;
  int stride = gridDim.x * blockDim.x;
  for (int i = blockIdx.x*blockDim.x + threadIdx.x; i < tot; i += stride){
    const f32x4* xp = (const f32x4*)x;
    f32x4 a = xp[2l*i], b2 = xp[2l*i+1];
    int c = (i*8) & (CC-1);
    u16 r[8];
    #pragma unroll
    for (int j = 0; j < 4; j++) r[j]   = f2bf(a[j] *scsh[c+j]   + scsh[CC+c+j]);
    #pragma unroll
    for (int j = 0; j < 4; j++) r[4+j] = f2bf(b2[j]*scsh[c+4+j] + scsh[CC+c+4+j]);
    *(bf16x8*)(xn + 8l*i) = *(bf16x8*)r;
  }
}

// ---------------- weight fp32 -> bf16 ----------------
__global__ __launch_bounds__(256) void wconv_k(const float* __restrict__ a, const float* __restrict__ b,
                                               const float* __restrict__ c, const float* __restrict__ d,
                                               u16* __restrict__ o){
  int i = blockIdx.x*256 + threadIdx.x;
  if (i >= 4*CC*CC) return;
  int w = i >> 18;  // CC*CC = 262144 = 2^18
  const float* src = w==0 ? a : (w==1 ? b : (w==2 ? c : d));
  o[i] = f2bf(src[i & (CC*CC-1)]);
}

// ---------------- 256x256-tile bf16 MFMA GEMM, 2-phase pipelined, BK=64 ----------------
// C[m,n] = sum_k A[m,k]*W[n,k].  8 K-tiles of 64, 2 LDS buffers (128 KiB), stage-1-ahead.
// Body t: STAGE(t+1) [8 gload_lds] -> slice0 reads (12 ds_read_b128, swizzled) ->
// lgkmcnt(0) -> 32 MFMA -> slice1 reads -> lgkmcnt(0) -> 32 MFMA -> vmcnt(0) -> barrier.
// vmcnt(0) is stall-free: tile t+1 was issued one full body (~2500 cyc) earlier.
// LDS swizzle: chunk' = chunk ^ ((row>>1)&7) on both the pre-swizzled global source
// (gload dest linear, rule 21) and the ds_read address; uniform 8 accesses/bank.
// T1: bijective chunked XCD swizzle (nwg divisible by 8).
template<int FINAL>
__global__ __launch_bounds__(512,2) void gemm2p_k(
    const u16* __restrict__ A,
    const u16* __restrict__ W0, const u16* __restrict__ W1, const u16* __restrict__ W2,
    u16* __restrict__ O0, u16* __restrict__ O1, u16* __restrict__ O2,
    const float* __restrict__ bias, const float* __restrict__ resid, float* __restrict__ out)
{
  __shared__ u16 lds[2*32768];   // per buf: A 256x64 (16384 u16) + B 256x64
  const int NTX = FINAL ? 2 : 6;
  const int CH  = FINAL ? 124 : 372;   // nwg/8 (992, 2976 both divisible by 8)
  int lin = blockIdx.x + NTX*blockIdx.y;
  int swz = (lin & 7)*CH + (lin >> 3);
  int bx = swz % NTX, by = swz / NTX;

  const int t = threadIdx.x;
  const int mt = by * 256;
  int nt; const u16* Wsel; u16* Osel = nullptr;
  if (FINAL) { Wsel = W0; nt = bx; }
  else {
    int wi = bx >> 1; nt = bx & 1;
    Wsel = wi==0 ? W0 : (wi==1 ? W1 : W2);
    Osel = wi==0 ? O0 : (wi==1 ? O1 : O2);
  }
  const u16* Ab = A    + (long)mt*CC;
  const u16* Bb = Wsel + (long)nt*256*CC;
  const int lane = t & 63;
  const int wv = t >> 6, wm = wv >> 2, wn = wv & 3;   // 2x4 wave grid, wave tile 128x64
  const int lr = lane & 15, hi = lane >> 4;
  const int srow = t >> 3;                 // staging row 0..63 (per 64-row round)
  const int sc   = t & 7;                  // dest 16B chunk within 128B row
  const int sg   = sc ^ ((t >> 4) & 7);    // pre-swizzled source chunk ((row>>1)&7)

  f32x4 acc[8][4];
  #pragma unroll
  for (int m=0;m<8;m++)
    #pragma unroll
    for (int n=0;n<4;n++)
      acc[m][n] = (f32x4){0.f,0.f,0.f,0.f};

  auto STAGE = [&](int kt){
    u16* dst = &lds[(kt & 1) * 32768];
    const u16* As = Ab + kt*64 + sg*8;
    const u16* Bs = Bb + kt*64 + sg*8;
    #pragma unroll
    for (int u=0;u<4;u++){
      int r = srow + 64*u;
      gload_lds16(As + (long)r*CC, &dst[r*64 + sc*8]);
    }
    #pragma unroll
    for (int u=0;u<4;u++){
      int r = srow + 64*u;
      gload_lds16(Bs + (long)r*CC, &dst[16384 + r*64 + sc*8]);
    }
  };

  STAGE(0);
  asm volatile("s_waitcnt vmcnt(0)" ::: "memory");
  asm volatile("s_barrier" ::: "memory");

  const int rsw = (lr >> 1) & 7;           // read-side row swizzle key
  #pragma unroll 1
  for (int kt = 0; kt < 8; ++kt){
    if (kt < 7) STAGE(kt + 1);
    const u16* Al = &lds[(kt & 1) * 32768];
    const u16* Bl = Al + 16384;
    #pragma unroll
    for (int ks = 0; ks < 2; ++ks){
      const int ch = (ks*4 + hi) ^ rsw;    // swizzled 16B chunk
      bf16x8 af[8], bfr[4];
      #pragma unroll
      for (int m=0;m<8;m++){
        int row = wm*128 + m*16 + lr;
        af[m] = *(const bf16x8*)&Al[row*64 + ch*8];
      }
      #pragma unroll
      for (int n=0;n<4;n++){
        int row = wn*64 + n*16 + lr;
        bfr[n] = *(const bf16x8*)&Bl[row*64 + ch*8];
      }
      asm volatile("s_waitcnt lgkmcnt(0)" ::: "memory");
      __builtin_amdgcn_sched_barrier(0);   // rule 18: MFMAs stay below the lgkmcnt
      __builtin_amdgcn_s_setprio(1);
      #pragma unroll
      for (int m=0;m<8;m++)
        #pragma unroll
        for (int n=0;n<4;n++)
          acc[m][n] = __builtin_amdgcn_mfma_f32_16x16x32_bf16(af[m], bfr[n], acc[m][n], 0, 0, 0);
      __builtin_amdgcn_s_setprio(0);
    }
    if (kt < 7){
      asm volatile("s_waitcnt vmcnt(0)" ::: "memory");  // tile kt+1 landed (issued ~1 body ago)
      asm volatile("s_barrier" ::: "memory");
    }
  }

  #pragma unroll
  for (int m=0;m<8;m++){
    int gr = mt + wm*128 + m*16 + hi*4;
    #pragma unroll
    for (int n=0;n<4;n++){
      int gc = nt*256 + wn*64 + n*16 + lr;
      #pragma unroll
      for (int j=0;j<4;j++){
        long off = (long)(gr + j)*CC + gc;
        if (FINAL) out[off] = acc[m][n][j] + bias[gc] + resid[off];
        else       Osel[off] = f2bf(acc[m][n][j]);
      }
    }
  }
}

// ---------------- energy: one wave per (b,h); 32x32 padded, 8 MFMAs ----------------
__global__ __launch_bounds__(256) void energy_k(const u16* __restrict__ q, const u16* __restrict__ k,
                                                float* __restrict__ e){
  const int wv = threadIdx.x >> 6, lane = threadIdx.x & 63;
  const int lr = lane & 15, hi = lane >> 4;
  #pragma unroll 1
  for (int it = 0; it < 4; it++){
    int p = blockIdx.x*4 + wv + 8192*it;   // 0..32767
    int b = p >> 3, h = p & 7;
    long base = ((long)b*SS)*CC + h*64;
    bf16x8 aq[2][2], ak[2][2];
    #pragma unroll
    for (int m=0;m<2;m++){
      int s = m*16 + lr;
      #pragma unroll
      for (int ks=0;ks<2;ks++){
        bf16x8 z = {0,0,0,0,0,0,0,0};
        aq[m][ks] = z; ak[m][ks] = z;
        if (s < SS){
          aq[m][ks] = *(const bf16x8*)&q[base + (long)s*CC + ks*32 + hi*8];
          ak[m][ks] = *(const bf16x8*)&k[base + (long)s*CC + ks*32 + hi*8];
        }
      }
    }
    f32x4 acc[2][2];
    #pragma unroll
    for (int m=0;m<2;m++)
      #pragma unroll
      for (int n=0;n<2;n++)
        acc[m][n] = (f32x4){0.f,0.f,0.f,0.f};
    #pragma unroll
    for (int ks=0;ks<2;ks++)
      #pragma unroll
      for (int m=0;m<2;m++)
        #pragma unroll
        for (int n=0;n<2;n++)
          acc[m][n] = __builtin_amdgcn_mfma_f32_16x16x32_bf16(aq[m][ks], ak[n][ks], acc[m][n], 0, 0, 0);
    long eb = (long)p*SSQ;
    #pragma unroll
    for (int m=0;m<2;m++)
      #pragma unroll
      for (int n=0;n<2;n++)
        #pragma unroll
        for (int j=0;j<4;j++){
          int s = m*16 + hi*4 + j, s2 = n*16 + lr;
          if (s < SS && s2 < SS) e[eb + s*SS + s2] = acc[m][n][j];
        }
  }
}

// ---------------- BN2 stats over (b,h) per (s,s') ----------------
__global__ __launch_bounds__(256) void bn2_stats_k(const float* __restrict__ e, float* __restrict__ acc2){
  int p = blockIdx.x*256 + threadIdx.x;  // position
  if (p >= SSQ) return;
  float s = 0.f, q = 0.f;
  int r0 = blockIdx.y * 128;
  for (int r = r0; r < r0 + 128; r++){
    float v = e[(long)r*SSQ + p];
    s += v; q += v*v;
  }
  atomicAdd(&acc2[p], s);
  atomicAdd(&acc2[1024 + p], q);
}

__global__ __launch_bounds__(256) void bn2_final_k(const float* __restrict__ acc2, const float* __restrict__ pw,
                                                   const float* __restrict__ pb, float* __restrict__ ss2){
  int p = blockIdx.x*256 + threadIdx.x;
  if (p >= SSQ) return;
  const float invN = 1.f/32768.f;
  const float invs = 0.04419417382415922f; // 1/sqrt(512)
  float mu  = acc2[p]*invN;
  float var = acc2[1024+p]*invN - mu*mu;
  float rs  = rsqrtf(var + 1e-5f);
  float srp = rs * pw[p];
  ss2[p]      = srp * invs;                 // scale on e (pen_w and 1/sqrt(C) folded)
  ss2[1024+p] = (pb[p] - mu*srp) * invs;    // shift
}

// ---------------- normalize + softmax + PV, one wave per (b,h) ----------------
__global__ __launch_bounds__(256) void attn_pv_k(const float* __restrict__ e, const float* __restrict__ ss2,
                                                 const u16* __restrict__ v, u16* __restrict__ ctx){
  __shared__ float sc2[SSQ], sh2[SSQ];
  __shared__ float att[4][SSQ];
  for (int i = threadIdx.x; i < SSQ; i += 256){ sc2[i] = ss2[i]; sh2[i] = ss2[1024+i]; }
  __syncthreads();
  const int wv = threadIdx.x >> 6, lane = threadIdx.x & 63;
  #pragma unroll 1
  for (int it = 0; it < 4; it++){
    int p = blockIdx.x*4 + wv + 8192*it;
    int b = p >> 3, h = p & 7;
    long eb = (long)p*SSQ;
    for (int i = lane; i < SSQ; i += 64)
      att[wv][i] = e[eb + i]*sc2[i] + sh2[i];      // normalized logits (already / sqrt(C))
    __syncthreads();
    {
      // wave-parallel softmax: 2 lanes per row, shfl_xor(1) combine
      int r = lane >> 1, half = lane & 1;
      if (r < SS){
        int ro = r*SS;
        int j0 = half*16, j1 = half ? SS : 16;
        float mx = -1e30f;
        for (int j=j0;j<j1;j++) mx = fmaxf(mx, att[wv][ro + j]);
        mx = fmaxf(mx, __shfl_xor(mx, 1));
        float sum = 0.f;
        for (int j=j0;j<j1;j++) sum += __expf(att[wv][ro + j] - mx);
        sum += __shfl_xor(sum, 1);
        float inv = 1.f / sum;
        for (int j=j0;j<j1;j++) att[wv][ro + j] = __expf(att[wv][ro + j] - mx) * inv;
      }
    }
    __syncthreads();
    // PV: lane = head-dim channel
    long vbase = ((long)b*SS)*CC + h*64 + lane;
    float vr[SS];
    #pragma unroll
    for (int j=0;j<SS;j++) vr[j] = bf2f(v[vbase + (long)j*CC]);
    #pragma unroll 1
    for (int s=0;s<SS;s++){
      float c = 0.f;
      #pragma unroll
      for (int j=0;j<SS;j++) c += att[wv][s*SS + j] * vr[j];
      ctx[vbase + (long)s*CC] = f2bf(c);
    }
    __syncthreads();
  }
}

extern "C" void kernel_launch(void* const* d_in, const int* in_sizes, int n_in,
                              void* d_out, int out_size, void* d_ws, size_t ws_size,
                              hipStream_t stream)
{
  const float* x      = (const float*)d_in[0];
  const float* norm_w = (const float*)d_in[1];
  const float* norm_b = (const float*)d_in[2];
  const float* Wq     = (const float*)d_in[3];
  const float* Wk     = (const float*)d_in[4];
  const float* Wv     = (const float*)d_in[5];
  const float* Wout   = (const float*)d_in[6];
  const float* b_out  = (const float*)d_in[7];
  const float* pen_w  = (const float*)d_in[8];
  const float* pen_b  = (const float*)d_in[9];
  float* out = (float*)d_out;

  char* ws = (char*)d_ws;
  // workspace layout (bytes)
  const size_t WQB   = 0;                    // 4 weights bf16, contiguous: 4*262144*2 = 2 MB
  const size_t STATS = 2097152;              // zeroed region, 16 KB: bn1 sums [1024] f32 @+0, bn2 sums [2048] f32 @+4096
  const size_t SCSH1 = STATS + 16384;        // bn1 scale/shift [1024] f32
  const size_t SS2O  = SCSH1 + 4096;         // bn2 scale2/shift2 [2048] f32
  const size_t BIG0  = 2129920;              // xn bf16 (130,023,424 B); later aliased by energy f32 (125,960,192 B)
  const size_t BIGSZ = 130023424;
  u16*   wq    = (u16*)(ws + WQB);
  float* stats = (float*)(ws + STATS);
  float* acc2  = (float*)(ws + STATS + 4096);
  float* scsh  = (float*)(ws + SCSH1);
  float* ss2   = (float*)(ws + SS2O);
  u16*   xn    = (u16*)(ws + BIG0);
  float* e     = (float*)(ws + BIG0);            // alias: xn dead after QKV GEMM
  u16*   qb    = (u16*)(ws + BIG0 + BIGSZ);
  u16*   kb    = (u16*)(ws + BIG0 + 2*BIGSZ);
  u16*   vb    = (u16*)(ws + BIG0 + 3*BIGSZ);
  u16*   ctx   = qb;                             // alias: q dead after energy

  (void)hipMemsetAsync(ws + STATS, 0, 16384, stream);
  wconv_k<<<4096, 256, 0, stream>>>(Wq, Wk, Wv, Wout, wq);
  bn1_stats_k<<<512, 256, 0, stream>>>(x, stats);
  bn1_final_k<<<1, 512, 0, stream>>>(stats, norm_w, norm_b, scsh);
  bn1_apply_k<<<2048, 256, 0, stream>>>(x, scsh, xn);
  gemm2p_k<0><<<dim3(6, 496), 512, 0, stream>>>(xn, wq, wq + 262144, wq + 2*262144,
                                                qb, kb, vb, nullptr, nullptr, nullptr);
  energy_k<<<2048, 256, 0, stream>>>(qb, kb, e);
  bn2_stats_k<<<dim3(4, 256), 256, 0, stream>>>(e, acc2);
  bn2_final_k<<<4, 256, 0, stream>>>(acc2, pen_w, pen_b, ss2);
  attn_pv_k<<<2048, 256, 0, stream>>>(e, ss2, vb, ctx);
  gemm2p_k<1><<<dim3(2, 496), 512, 0, stream>>>(ctx, wq + 3*262144, nullptr, nullptr,
                                                nullptr, nullptr, nullptr, b_out, x, out);
}